// Round 8
// baseline (521.240 us; speedup 1.0000x reference)
//
#include <hip/hip_runtime.h>
#include <hip/hip_bf16.h>
#include <stdint.h>

#define T_DIM 8192
#define E_DIM 1024
#define H_DIM 64
#define NEGF  -3.0e38f
// 0.125 (1/sqrt(64)) * log2(e): softmax computed in base-2 domain
#define SC_LOG2 0.18033688011112042f

typedef __attribute__((ext_vector_type(8))) short bf16x8;
typedef __attribute__((ext_vector_type(4))) float f32x4;

// v_exp_f32 computes 2^x; __exp2f collides with glibc math.h macros -> use builtin
static __device__ __forceinline__ float fexp2(float x) { return __builtin_amdgcn_exp2f(x); }

static __device__ __forceinline__ uint32_t pk2(float x, float y) {
    __hip_bfloat162 h = __float22bfloat162_rn(make_float2(x, y));
    union { __hip_bfloat162 h2; uint32_t u; } c; c.h2 = h; return c.u;
}
static __device__ __forceinline__ bf16x8 pack8(float4 a, float4 b) {
    union { bf16x8 v; uint32_t u[4]; } c;
    c.u[0] = pk2(a.x, a.y); c.u[1] = pk2(a.z, a.w);
    c.u[2] = pk2(b.x, b.y); c.u[3] = pk2(b.z, b.w);
    return c.v;
}
static __device__ __forceinline__ bf16x8 mk8(uint32_t a, uint32_t b, uint32_t c, uint32_t d) {
    union { bf16x8 v; uint32_t u[4]; } t;
    t.u[0] = a; t.u[1] = b; t.u[2] = c; t.u[3] = d;
    return t.v;
}
static __device__ __forceinline__ uint16_t bf1(float x) {
    __hip_bfloat16 h = __float2bfloat16(x);
    union { __hip_bfloat16 h1; uint16_t s; } c; c.h1 = h; return c.s;
}

// ============ W fp32 -> bf16 pre-conversion (3 x 64 x 1024, one-shot) ============
__global__ __launch_bounds__(256) void wconv_kernel(
    const float* __restrict__ Wq, const float* __restrict__ Wk, const float* __restrict__ Wv,
    uint16_t* __restrict__ Wqb, uint16_t* __restrict__ Wkb, uint16_t* __restrict__ Wvb)
{
    const int idx = blockIdx.x * 256 + threadIdx.x;      // 49152 threads, 4 floats each
    const int which = idx / 16384;                       // 65536 floats per matrix
    const int off = (idx & 16383) * 4;
    const float* W = (which == 0) ? Wq : (which == 1) ? Wk : Wv;
    uint16_t* Wb   = (which == 0) ? Wqb : (which == 1) ? Wkb : Wvb;
    float4 w = *(const float4*)(W + off);
    uint2 o = make_uint2(pk2(w.x, w.y), pk2(w.z, w.w));
    *(uint2*)(Wb + off) = o;
}

// ============ projection GEMM: O = X @ W^T (fp32 X, bf16 W -> bf16 out) ============
// r7 verbatim (known-good): 256 thr, 4 waves = 4 t-subtiles, full K per wave.
__global__ __launch_bounds__(256) void proj_kernel(
    const float* __restrict__ Xq, const float* __restrict__ Xk, const float* __restrict__ Xv,
    const uint16_t* __restrict__ Wqb, const uint16_t* __restrict__ Wkb, const uint16_t* __restrict__ Wvb,
    uint16_t* __restrict__ Qb, uint16_t* __restrict__ Kb, uint16_t* __restrict__ Vtb)
{
    __shared__ float TD[64][69];   // V-transpose staging (stride 69: <=2-way banks)

    const int mat = blockIdx.y;
    const float* X    = (mat == 0) ? Xq  : (mat == 1) ? Xk  : Xv;
    const uint16_t* W = (mat == 0) ? Wqb : (mat == 1) ? Wkb : Wvb;

    const int tid  = threadIdx.x;
    const int wv   = tid >> 6;        // wave 0..3 -> t-subtile
    const int lane = tid & 63;
    const int lidx = lane & 15;
    const int quad = lane >> 4;
    const int t0   = blockIdx.x * 64 + wv * 16;

    const float* Xr = X + (size_t)(t0 + lidx) * E_DIM + quad * 8;

    f32x4 acc[4] = {{0,0,0,0},{0,0,0,0},{0,0,0,0},{0,0,0,0}};
    for (int k0 = 0; k0 < E_DIM; k0 += 32) {
        float4 x0 = *(const float4*)(Xr + k0);
        float4 x1 = *(const float4*)(Xr + k0 + 4);
        bf16x8 xa = pack8(x0, x1);
        #pragma unroll
        for (int nt = 0; nt < 4; ++nt) {
            const uint16_t* Wr = W + (size_t)(nt * 16 + lidx) * E_DIM + k0 + quad * 8;
            bf16x8 wb = *(const bf16x8*)Wr;
            acc[nt] = __builtin_amdgcn_mfma_f32_16x16x32_bf16(xa, wb, acc[nt], 0, 0, 0);
        }
    }

    if (mat < 2) {
        uint16_t* O = (mat == 0) ? Qb : Kb;
        #pragma unroll
        for (int nt = 0; nt < 4; ++nt)
            #pragma unroll
            for (int r = 0; r < 4; ++r)
                O[(size_t)(t0 + quad * 4 + r) * H_DIM + nt * 16 + lidx] = bf1(acc[nt][r]);
    } else {
        #pragma unroll
        for (int nt = 0; nt < 4; ++nt)
            #pragma unroll
            for (int r = 0; r < 4; ++r)
                TD[wv * 16 + quad * 4 + r][nt * 16 + lidx] = acc[nt][r];
        __syncthreads();
        const int h = tid >> 2, tq = tid & 3;   // h 0..63, 16 t-values each
        uint32_t w8[8];
        #pragma unroll
        for (int i = 0; i < 8; ++i)
            w8[i] = pk2(TD[tq * 16 + 2 * i][h], TD[tq * 16 + 2 * i + 1][h]);
        uint16_t* dst = Vtb + (size_t)h * T_DIM + blockIdx.x * 64 + tq * 16;
        uint4 lo = make_uint4(w8[0], w8[1], w8[2], w8[3]);
        uint4 hi = make_uint4(w8[4], w8[5], w8[6], w8[7]);
        *(uint4*)dst       = lo;
        *(uint4*)(dst + 8) = hi;
    }
}

// ============ causal flash attention, MFMA bf16, S^T formulation ============
// S^T = K·Q^T so softmax rows live per-lane (q = lane&15): 2 shuffles per
// reduction, P already in A-frag layout for PV via k-slot permutation ->
// ZERO LDS traffic in the k-loop. 4 waves split the key range; LDS merge.
__global__ __launch_bounds__(256) void flash_kernel(
    const uint16_t* __restrict__ Qb, const uint16_t* __restrict__ Kb,
    const uint16_t* __restrict__ Vtb, float* __restrict__ Out)
{
    __shared__ __align__(16) float WS[4][16][68];
    __shared__ float Mw[4][16];
    __shared__ float Lw[4][16];

    const int tid  = threadIdx.x;
    const int wv   = tid >> 6;
    const int lane = tid & 63;
    const int lidx = lane & 15;
    const int quad = lane >> 4;

    const int qt = 511 - (int)blockIdx.x;   // big tiles first
    const int q0 = qt * 16;
    const int qg = q0 + lidx;               // this lane's global q row

    // Q fragment (acts as B operand of S^T = K·Q^T): lane holds Q[q0+lidx][quad*8+j]
    bf16x8 bq0 = *(const bf16x8*)(Qb + (size_t)qg * H_DIM + quad * 8);
    bf16x8 bq1 = *(const bf16x8*)(Qb + (size_t)qg * H_DIM + 32 + quad * 8);

    const int ktiles  = qt / 4 + 1;
    const int base    = ktiles >> 2;
    const int rem     = ktiles & 3;
    const int myn     = base + (wv < rem ? 1 : 0);
    const int mystart = wv * base + (wv < rem ? wv : rem);

    float m = NEGF, l = 0.f;
    f32x4 o[4] = {{0,0,0,0},{0,0,0,0},{0,0,0,0},{0,0,0,0}};   // o[ht]: O[q=quad*4+r][ht*16+lidx]

    for (int it = 0; it < myn; ++it) {
        const int kt = mystart + it;
        const int s0 = kt * 64;

        // ---- S^T = K · Q^T : lane gets S[qg][s0 + nt*16 + quad*4 + r] ----
        f32x4 s[4];
        #pragma unroll
        for (int nt = 0; nt < 4; ++nt) {
            const uint16_t* kr = Kb + (size_t)(s0 + nt * 16 + lidx) * H_DIM + quad * 8;
            bf16x8 a0 = *(const bf16x8*)(kr);
            bf16x8 a1 = *(const bf16x8*)(kr + 32);
            f32x4 z = {0, 0, 0, 0};
            s[nt] = __builtin_amdgcn_mfma_f32_16x16x32_bf16(a0, bq0, z, 0, 0, 0);
            s[nt] = __builtin_amdgcn_mfma_f32_16x16x32_bf16(a1, bq1, s[nt], 0, 0, 0);
        }

        // ---- scale (base-2 domain) + causal mask on the diagonal tile ----
        if (kt == ktiles - 1) {
            #pragma unroll
            for (int nt = 0; nt < 4; ++nt)
                #pragma unroll
                for (int r = 0; r < 4; ++r) {
                    const int key = s0 + nt * 16 + quad * 4 + r;
                    s[nt][r] = (key <= qg) ? s[nt][r] * SC_LOG2 : NEGF;
                }
        } else {
            #pragma unroll
            for (int nt = 0; nt < 4; ++nt)
                #pragma unroll
                for (int r = 0; r < 4; ++r)
                    s[nt][r] *= SC_LOG2;
        }

        // ---- online softmax: in-lane over 16 keys, then 2 cross-quad shuffles ----
        float mt = NEGF;
        #pragma unroll
        for (int nt = 0; nt < 4; ++nt)
            #pragma unroll
            for (int r = 0; r < 4; ++r)
                mt = fmaxf(mt, s[nt][r]);
        mt = fmaxf(mt, __shfl_xor(mt, 16));
        mt = fmaxf(mt, __shfl_xor(mt, 32));
        // clamp: a fully-masked lane-row must yield p=0, not exp2(NEGF-NEGF)=1
        const float mn = fmaxf(fmaxf(m, mt), -1.0e30f);
        const float alpha = fexp2(m - mn);
        m = mn;

        float p[4][4];
        float ps = 0.f;
        #pragma unroll
        for (int nt = 0; nt < 4; ++nt)
            #pragma unroll
            for (int r = 0; r < 4; ++r) {
                p[nt][r] = fexp2(s[nt][r] - mn);
                ps += p[nt][r];
            }
        ps += __shfl_xor(ps, 16);
        ps += __shfl_xor(ps, 32);
        l = l * alpha + ps;

        // alpha for accumulator rows q=quad*4+r (held by lane quad*4+r; alpha is
        // quad-uniform per lidx after the xor16/32 reductions)
        float av[4];
        #pragma unroll
        for (int r = 0; r < 4; ++r) av[r] = __shfl(alpha, quad * 4 + r);
        #pragma unroll
        for (int ht = 0; ht < 4; ++ht)
            #pragma unroll
            for (int r = 0; r < 4; ++r)
                o[ht][r] *= av[r];

        // ---- P A-frags (k-slot permuted: j=0..3 <- tile 2t, j=4..7 <- tile 2t+1) ----
        bf16x8 ap0 = pack8(make_float4(p[0][0], p[0][1], p[0][2], p[0][3]),
                           make_float4(p[1][0], p[1][1], p[1][2], p[1][3]));
        bf16x8 ap1 = pack8(make_float4(p[2][0], p[2][1], p[2][2], p[2][3]),
                           make_float4(p[3][0], p[3][1], p[3][2], p[3][3]));

        // ---- O += P·V with matching k-slot permutation on V's B-frag ----
        #pragma unroll
        for (int t = 0; t < 2; ++t) {
            const bf16x8 ap = t ? ap1 : ap0;
            #pragma unroll
            for (int ht = 0; ht < 4; ++ht) {
                const uint16_t* vr = Vtb + (size_t)(ht * 16 + lidx) * T_DIM + s0 + 32 * t + quad * 4;
                uint2 va = *(const uint2*)(vr);        // keys of tile 2t
                uint2 vb = *(const uint2*)(vr + 16);   // keys of tile 2t+1
                bf16x8 bv = mk8(va.x, va.y, vb.x, vb.y);
                o[ht] = __builtin_amdgcn_mfma_f32_16x16x32_bf16(ap, bv, o[ht], 0, 0, 0);
            }
        }
    }

    // ---- publish per-wave partials, merge across the 4 waves ----
    if (quad == 0) { Mw[wv][lidx] = m; Lw[wv][lidx] = l; }
    #pragma unroll
    for (int ht = 0; ht < 4; ++ht)
        #pragma unroll
        for (int r = 0; r < 4; ++r)
            WS[wv][quad * 4 + r][ht * 16 + lidx] = o[ht][r];
    __syncthreads();

    const int row = tid >> 4, cg = tid & 15;
    float M = fmaxf(fmaxf(Mw[0][row], Mw[1][row]), fmaxf(Mw[2][row], Mw[3][row]));
    float L = 0.f;
    float ox = 0.f, oy = 0.f, oz = 0.f, ow = 0.f;
    #pragma unroll
    for (int w2 = 0; w2 < 4; ++w2) {
        const float sc = fexp2(Mw[w2][row] - M);   // empty/masked wave -> 0
        L += Lw[w2][row] * sc;
        float4 t = *(const float4*)&WS[w2][row][cg * 4];
        ox += t.x * sc; oy += t.y * sc; oz += t.z * sc; ow += t.w * sc;
    }
    const float inv = 1.f / L;
    float4 ov = make_float4(ox * inv, oy * inv, oz * inv, ow * inv);
    *(float4*)(Out + (size_t)(q0 + row) * H_DIM + cg * 4) = ov;
}

extern "C" void kernel_launch(void* const* d_in, const int* in_sizes, int n_in,
                              void* d_out, int out_size, void* d_ws, size_t ws_size,
                              hipStream_t stream) {
    (void)in_sizes; (void)n_in; (void)out_size; (void)ws_size;
    const float* Xq = (const float*)d_in[0];
    const float* Xk = (const float*)d_in[1];
    const float* Xv = (const float*)d_in[2];
    // d_in[3] = mask: causal triu(k=1), hard-coded
    const float* Wq = (const float*)d_in[4];
    const float* Wk = (const float*)d_in[5];
    const float* Wv = (const float*)d_in[6];

    uint16_t* Qb  = (uint16_t*)d_ws;                       // [8192][64] bf16
    uint16_t* Kb  = Qb + (size_t)T_DIM * H_DIM;            // [8192][64] bf16
    uint16_t* Vtb = Kb + (size_t)T_DIM * H_DIM;            // [64][8192] bf16
    uint16_t* Wqb = Vtb + (size_t)T_DIM * H_DIM;           // [64][1024] bf16 x3
    uint16_t* Wkb = Wqb + (size_t)H_DIM * E_DIM;
    uint16_t* Wvb = Wkb + (size_t)H_DIM * E_DIM;

    wconv_kernel<<<192, 256, 0, stream>>>(Wq, Wk, Wv, Wqb, Wkb, Wvb);

    dim3 pgrid(T_DIM / 64, 3);
    proj_kernel<<<pgrid, 256, 0, stream>>>(Xq, Xk, Xv, Wqb, Wkb, Wvb, Qb, Kb, Vtb);

    flash_kernel<<<T_DIM / 16, 256, 0, stream>>>(Qb, Kb, Vtb, (float*)d_out);
}

// Round 9
// 465.559 us; speedup vs baseline: 1.1196x; 1.1196x over previous
//
#include <hip/hip_runtime.h>
#include <hip/hip_bf16.h>
#include <stdint.h>

#define T_DIM 8192
#define E_DIM 1024
#define H_DIM 64
#define NEGF  -3.0e38f

typedef __attribute__((ext_vector_type(8))) short bf16x8;
typedef __attribute__((ext_vector_type(4))) float f32x4;

static __device__ __forceinline__ uint32_t pk2(float x, float y) {
    __hip_bfloat162 h = __float22bfloat162_rn(make_float2(x, y));
    union { __hip_bfloat162 h2; uint32_t u; } c; c.h2 = h; return c.u;
}
static __device__ __forceinline__ bf16x8 pack8(float4 a, float4 b) {
    union { bf16x8 v; uint32_t u[4]; } c;
    c.u[0] = pk2(a.x, a.y); c.u[1] = pk2(a.z, a.w);
    c.u[2] = pk2(b.x, b.y); c.u[3] = pk2(b.z, b.w);
    return c.v;
}
static __device__ __forceinline__ uint16_t bf1(float x) {
    __hip_bfloat16 h = __float2bfloat16(x);
    union { __hip_bfloat16 h1; uint16_t s; } c; c.h1 = h; return c.s;
}

// ============ W fp32 -> bf16 pre-conversion (3 x 64 x 1024, one-shot) ============
__global__ __launch_bounds__(256) void wconv_kernel(
    const float* __restrict__ Wq, const float* __restrict__ Wk, const float* __restrict__ Wv,
    uint16_t* __restrict__ Wqb, uint16_t* __restrict__ Wkb, uint16_t* __restrict__ Wvb)
{
    const int idx = blockIdx.x * 256 + threadIdx.x;      // 49152 threads, 4 floats each
    const int which = idx / 16384;                       // 65536 floats per matrix
    const int off = (idx & 16383) * 4;
    const float* W = (which == 0) ? Wq : (which == 1) ? Wk : Wv;
    uint16_t* Wb   = (which == 0) ? Wqb : (which == 1) ? Wkb : Wvb;
    float4 w = *(const float4*)(W + off);
    uint2 o = make_uint2(pk2(w.x, w.y), pk2(w.z, w.w));
    *(uint2*)(Wb + off) = o;
}

// ============ projection GEMM: O = X @ W^T (fp32 X, bf16 W -> bf16 out) ============
// r7 verbatim (known-good): 256 thr, 4 waves = 4 t-subtiles, full K per wave.
__global__ __launch_bounds__(256) void proj_kernel(
    const float* __restrict__ Xq, const float* __restrict__ Xk, const float* __restrict__ Xv,
    const uint16_t* __restrict__ Wqb, const uint16_t* __restrict__ Wkb, const uint16_t* __restrict__ Wvb,
    uint16_t* __restrict__ Qb, uint16_t* __restrict__ Kb, uint16_t* __restrict__ Vtb)
{
    __shared__ float TD[64][69];   // V-transpose staging (stride 69: <=2-way banks)

    const int mat = blockIdx.y;
    const float* X    = (mat == 0) ? Xq  : (mat == 1) ? Xk  : Xv;
    const uint16_t* W = (mat == 0) ? Wqb : (mat == 1) ? Wkb : Wvb;

    const int tid  = threadIdx.x;
    const int wv   = tid >> 6;        // wave 0..3 -> t-subtile
    const int lane = tid & 63;
    const int lidx = lane & 15;
    const int quad = lane >> 4;
    const int t0   = blockIdx.x * 64 + wv * 16;

    const float* Xr = X + (size_t)(t0 + lidx) * E_DIM + quad * 8;

    f32x4 acc[4] = {{0,0,0,0},{0,0,0,0},{0,0,0,0},{0,0,0,0}};
    for (int k0 = 0; k0 < E_DIM; k0 += 32) {
        float4 x0 = *(const float4*)(Xr + k0);
        float4 x1 = *(const float4*)(Xr + k0 + 4);
        bf16x8 xa = pack8(x0, x1);
        #pragma unroll
        for (int nt = 0; nt < 4; ++nt) {
            const uint16_t* Wr = W + (size_t)(nt * 16 + lidx) * E_DIM + k0 + quad * 8;
            bf16x8 wb = *(const bf16x8*)Wr;
            acc[nt] = __builtin_amdgcn_mfma_f32_16x16x32_bf16(xa, wb, acc[nt], 0, 0, 0);
        }
    }

    if (mat < 2) {
        uint16_t* O = (mat == 0) ? Qb : Kb;
        #pragma unroll
        for (int nt = 0; nt < 4; ++nt)
            #pragma unroll
            for (int r = 0; r < 4; ++r)
                O[(size_t)(t0 + quad * 4 + r) * H_DIM + nt * 16 + lidx] = bf1(acc[nt][r]);
    } else {
        #pragma unroll
        for (int nt = 0; nt < 4; ++nt)
            #pragma unroll
            for (int r = 0; r < 4; ++r)
                TD[wv * 16 + quad * 4 + r][nt * 16 + lidx] = acc[nt][r];
        __syncthreads();
        const int h = tid >> 2, tq = tid & 3;   // h 0..63, 16 t-values each
        uint32_t w8[8];
        #pragma unroll
        for (int i = 0; i < 8; ++i)
            w8[i] = pk2(TD[tq * 16 + 2 * i][h], TD[tq * 16 + 2 * i + 1][h]);
        uint16_t* dst = Vtb + (size_t)h * T_DIM + blockIdx.x * 64 + tq * 16;
        uint4 lo = make_uint4(w8[0], w8[1], w8[2], w8[3]);
        uint4 hi = make_uint4(w8[4], w8[5], w8[6], w8[7]);
        *(uint4*)dst       = lo;
        *(uint4*)(dst + 8) = hi;
    }
}

// ============ causal flash attention, MFMA bf16 ============
// r7 body, but 8 waves per block (512 thr): key range split 8 ways ->
// 4 waves/SIMD resident (vs 2) to hide the K/V^T L2 gather latency.
__global__ __launch_bounds__(512) void flash_kernel(
    const uint16_t* __restrict__ Qb, const uint16_t* __restrict__ Kb,
    const uint16_t* __restrict__ Vtb, float* __restrict__ Out)
{
    __shared__ __align__(16) float WS[8][16][68];
    __shared__ float Mw[8][16];
    __shared__ float Lw[8][16];

    const int tid  = threadIdx.x;
    const int wv   = tid >> 6;        // 0..7
    const int lane = tid & 63;
    const int lidx = lane & 15;
    const int quad = lane >> 4;

    const int qt = 511 - (int)blockIdx.x;   // big tiles first
    const int q0 = qt * 16;

    // Q A-frags, live across whole k-loop
    bf16x8 aq0 = *(const bf16x8*)(Qb + (size_t)(q0 + lidx) * H_DIM + quad * 8);
    bf16x8 aq1 = *(const bf16x8*)(Qb + (size_t)(q0 + lidx) * H_DIM + 32 + quad * 8);

    const int ktiles  = qt / 4 + 1;
    const int base    = ktiles >> 3;
    const int rem     = ktiles & 7;
    const int myn     = base + (wv < rem ? 1 : 0);
    const int mystart = wv * base + (wv < rem ? wv : rem);

    float m[4] = {NEGF, NEGF, NEGF, NEGF};
    float l[4] = {0.f, 0.f, 0.f, 0.f};
    f32x4 o[4] = {{0,0,0,0},{0,0,0,0},{0,0,0,0},{0,0,0,0}};

    for (int it = 0; it < myn; ++it) {
        const int kt = mystart + it;
        const int s0 = kt * 64;

        // ---- S = Q K^T (16 x 64), B-frags straight from L2-resident bf16 K ----
        f32x4 s[4];
        #pragma unroll
        for (int nt = 0; nt < 4; ++nt) {
            const uint16_t* kr = Kb + (size_t)(s0 + nt * 16 + lidx) * H_DIM + quad * 8;
            bf16x8 b0 = *(const bf16x8*)(kr);
            bf16x8 b1 = *(const bf16x8*)(kr + 32);
            f32x4 z = {0, 0, 0, 0};
            s[nt] = __builtin_amdgcn_mfma_f32_16x16x32_bf16(aq0, b0, z, 0, 0, 0);
            s[nt] = __builtin_amdgcn_mfma_f32_16x16x32_bf16(aq1, b1, s[nt], 0, 0, 0);
        }

        // ---- scale + causal mask (only the diagonal tile is partial) ----
        if (kt == ktiles - 1) {
            #pragma unroll
            for (int nt = 0; nt < 4; ++nt)
                #pragma unroll
                for (int r = 0; r < 4; ++r) {
                    const int col = s0 + nt * 16 + lidx;
                    const int row = q0 + quad * 4 + r;
                    s[nt][r] = (col <= row) ? s[nt][r] * 0.125f : NEGF;
                }
        } else {
            #pragma unroll
            for (int nt = 0; nt < 4; ++nt)
                #pragma unroll
                for (int r = 0; r < 4; ++r)
                    s[nt][r] *= 0.125f;
        }

        // ---- online softmax (rows live in 16-lane groups; xor<16 stays inside) ----
        #pragma unroll
        for (int r = 0; r < 4; ++r) {
            float mt = fmaxf(fmaxf(s[0][r], s[1][r]), fmaxf(s[2][r], s[3][r]));
            mt = fmaxf(mt, __shfl_xor(mt, 1));
            mt = fmaxf(mt, __shfl_xor(mt, 2));
            mt = fmaxf(mt, __shfl_xor(mt, 4));
            mt = fmaxf(mt, __shfl_xor(mt, 8));
            const float mn = fmaxf(m[r], mt);
            const float al = __expf(m[r] - mn);
            m[r] = mn;
            float ps = 0.f;
            #pragma unroll
            for (int nt = 0; nt < 4; ++nt) {
                const float pv = __expf(s[nt][r] - mn);
                WS[wv][quad * 4 + r][nt * 16 + lidx] = pv;   // C-layout -> LDS
                ps += pv;
            }
            ps += __shfl_xor(ps, 1);
            ps += __shfl_xor(ps, 2);
            ps += __shfl_xor(ps, 4);
            ps += __shfl_xor(ps, 8);
            l[r] = l[r] * al + ps;
            #pragma unroll
            for (int nt = 0; nt < 4; ++nt) o[nt][r] *= al;
        }

        // ---- P: LDS round-trip to A-layout (wave-private, no barrier needed) ----
        const float* pr = &WS[wv][lidx][0];
        float4 p0 = *(const float4*)(pr + quad * 8);
        float4 p1 = *(const float4*)(pr + quad * 8 + 4);
        float4 p2 = *(const float4*)(pr + 32 + quad * 8);
        float4 p3 = *(const float4*)(pr + 32 + quad * 8 + 4);
        bf16x8 ap0 = pack8(p0, p1);
        bf16x8 ap1 = pack8(p2, p3);

        // ---- O += P V  (V^T rows read 16B/lane from L2) ----
        #pragma unroll
        for (int nt = 0; nt < 4; ++nt) {
            const uint16_t* vr = Vtb + (size_t)(nt * 16 + lidx) * T_DIM + s0 + quad * 8;
            bf16x8 v0 = *(const bf16x8*)(vr);
            bf16x8 v1 = *(const bf16x8*)(vr + 32);
            o[nt] = __builtin_amdgcn_mfma_f32_16x16x32_bf16(ap0, v0, o[nt], 0, 0, 0);
            o[nt] = __builtin_amdgcn_mfma_f32_16x16x32_bf16(ap1, v1, o[nt], 0, 0, 0);
        }
    }

    // ---- publish per-wave partials, merge across the 8 waves ----
    if (lidx == 0) {
        #pragma unroll
        for (int r = 0; r < 4; ++r) { Mw[wv][quad * 4 + r] = m[r]; Lw[wv][quad * 4 + r] = l[r]; }
    }
    #pragma unroll
    for (int nt = 0; nt < 4; ++nt)
        #pragma unroll
        for (int r = 0; r < 4; ++r)
            WS[wv][quad * 4 + r][nt * 16 + lidx] = o[nt][r];
    __syncthreads();

    // 512 threads: row = tid>>5 (0..15), cg = tid&31 (0..31), float2 per thread
    const int row = tid >> 5, cg = tid & 31;
    float M = NEGF;
    #pragma unroll
    for (int w2 = 0; w2 < 8; ++w2) M = fmaxf(M, Mw[w2][row]);
    float L = 0.f;
    float ox = 0.f, oy = 0.f;
    #pragma unroll
    for (int w2 = 0; w2 < 8; ++w2) {
        const float sc = __expf(Mw[w2][row] - M);   // empty wave: exp(-3e38)=0
        L += Lw[w2][row] * sc;
        float2 t = *(const float2*)&WS[w2][row][cg * 2];
        ox += t.x * sc; oy += t.y * sc;
    }
    const float inv = 1.f / L;
    *(float2*)(Out + (size_t)(q0 + row) * H_DIM + cg * 2) = make_float2(ox * inv, oy * inv);
}

extern "C" void kernel_launch(void* const* d_in, const int* in_sizes, int n_in,
                              void* d_out, int out_size, void* d_ws, size_t ws_size,
                              hipStream_t stream) {
    (void)in_sizes; (void)n_in; (void)out_size; (void)ws_size;
    const float* Xq = (const float*)d_in[0];
    const float* Xk = (const float*)d_in[1];
    const float* Xv = (const float*)d_in[2];
    // d_in[3] = mask: causal triu(k=1), hard-coded
    const float* Wq = (const float*)d_in[4];
    const float* Wk = (const float*)d_in[5];
    const float* Wv = (const float*)d_in[6];

    uint16_t* Qb  = (uint16_t*)d_ws;                       // [8192][64] bf16
    uint16_t* Kb  = Qb + (size_t)T_DIM * H_DIM;            // [8192][64] bf16
    uint16_t* Vtb = Kb + (size_t)T_DIM * H_DIM;            // [64][8192] bf16
    uint16_t* Wqb = Vtb + (size_t)T_DIM * H_DIM;           // [64][1024] bf16 x3
    uint16_t* Wkb = Wqb + (size_t)H_DIM * E_DIM;
    uint16_t* Wvb = Wkb + (size_t)H_DIM * E_DIM;

    wconv_kernel<<<192, 256, 0, stream>>>(Wq, Wk, Wv, Wqb, Wkb, Wvb);

    dim3 pgrid(T_DIM / 64, 3);
    proj_kernel<<<pgrid, 256, 0, stream>>>(Xq, Xk, Xv, Wqb, Wkb, Wvb, Qb, Kb, Vtb);

    flash_kernel<<<T_DIM / 16, 512, 0, stream>>>(Qb, Kb, Vtb, (float*)d_out);
}